// Round 17
// baseline (912.211 us; speedup 1.0000x reference)
//
#include <hip/hip_runtime.h>
#include <hip/hip_bf16.h>
#include <math.h>

// Problem: B=4, S=4096, D=1024.  M = B*S = 16384 rows.
// R14 -> R15 change: FFT LDS bank-conflict fix. float2 buf[1024] -> separate
// re/im float arrays with +1 pad every 32 elements (lpad(i)=i+(i>>5)).
// Measured R14: final_kernel SQ_LDS_BANK_CONFLICT=4.04e7 (~34% of cycles),
// VALUBusy 33%, HBM 11% -> LDS-conflict/latency bound. Per-stage analysis:
// stride classes at half<=8 were 8-16-way; padded split arrays are <=2-way
// (free, m136). Arithmetic bitwise-identical; GEMM/scan kernels untouched.
//
// Workspace: 202 MB (validated on HW).
//   kvp  : [M][D] float2  = 134217728 B
//   lin0 : [M][D] float   =  67108864 B
//   cs   : [B][16][D] f2  =    524288 B

#define MROWS 16384
#define ND    1024
#define SLEN  4096
#define NB    4
#define CHUNKS 16
#define CHLEN  256

#define WS_KVP_BYTES  (134217728ull)
#define WS_LIN_BYTES  (67108864ull)
#define WS_CS_BYTES   (524288ull)
#define WS_NEEDED     (WS_KVP_BYTES + WS_LIN_BYTES + WS_CS_BYTES)

typedef __attribute__((ext_vector_type(8))) short short8v;
typedef __attribute__((ext_vector_type(4))) float f32x4;

__device__ __forceinline__ float2 c_add(float2 a, float2 b) {
    return make_float2(a.x + b.x, a.y + b.y);
}
__device__ __forceinline__ float2 c_mul(float2 a, float2 b) {
    return make_float2(a.x * b.x - a.y * b.y, a.x * b.y + a.y * b.x);
}

// padded LDS index: +1 float every 32 -> breaks power-of-2 stride conflicts
__device__ __forceinline__ int lpad(int i) { return i + (i >> 5); }

// Split two fp32 into packed bf16 hi pair + bf16 lo pair.
__device__ __forceinline__ void split2(float f0, float f1,
                                       unsigned& hp, unsigned& lp)
{
    unsigned u0 = __float_as_uint(f0), u1 = __float_as_uint(f1);
    unsigned h0 = u0 & 0xFFFF0000u,  h1 = u1 & 0xFFFF0000u;
    float l0 = f0 - __uint_as_float(h0);
    float l1 = f1 - __uint_as_float(h1);
    hp = (u0 >> 16) | h1;
    lp = (__float_as_uint(l0) >> 16) | (__float_as_uint(l1) & 0xFFFF0000u);
}

// ---------------------------------------------------------------------------
// GEMM  out[m][n] = sum_k x[m][k]*W[n][k] + b[n]   (M=16384, N=K=1024)
// bf16 hi/lo-split MFMA 16x16x32 (R12 design, HW-verified R14: 3 launches
// drop out of top-5; absmax 4.77e-7 unchanged).
// ---------------------------------------------------------------------------
__global__ __launch_bounds__(256) void gemm_kernel(
    const float* __restrict__ x,
    const float* __restrict__ Wm, const float* __restrict__ bias,
    float* __restrict__ out)
{
    const int bm = blockIdx.y * 128;
    const int bn = blockIdx.x * 128;
    const int tid  = threadIdx.x;
    const int lane = tid & 63;
    const int wid  = tid >> 6;
    const int wr = wid >> 1, wc = wid & 1;     // wave quadrant (2x2 of 64x64)

    __shared__ __align__(16) short Ah[4][128][8];
    __shared__ __align__(16) short Al[4][128][8];
    __shared__ __align__(16) short Bh[4][128][8];
    __shared__ __align__(16) short Bl[4][128][8];

    f32x4 acc[4][4];
    #pragma unroll
    for (int i = 0; i < 4; i++)
        #pragma unroll
        for (int j = 0; j < 4; j++)
            acc[i][j] = (f32x4){0.f, 0.f, 0.f, 0.f};

    const int r   = tid >> 1;          // staging row 0..127
    const int kh  = (tid & 1) * 16;    // k offset 0 or 16 within BK=32
    const int kc0 = kh >> 3;           // LDS k-chunk 0 or 2

    const int kg = lane >> 4;          // fragment k-group 0..3
    const int fr = lane & 15;          // fragment row/col index

    for (int k0 = 0; k0 < 1024; k0 += 32) {
        const float* xs = x  + (size_t)(bm + r) * 1024 + k0 + kh;
        const float* wp = Wm + (size_t)(bn + r) * 1024 + k0 + kh;
        float fa[16], fb[16];
        #pragma unroll
        for (int q = 0; q < 4; q++) {
            *(float4*)&fa[q * 4] = *(const float4*)(xs + q * 4);
            *(float4*)&fb[q * 4] = *(const float4*)(wp + q * 4);
        }

        __syncthreads();   // previous iteration's fragment reads done

        unsigned ha[8], la[8], hb[8], lb[8];
        #pragma unroll
        for (int q = 0; q < 8; q++) {
            split2(fa[2*q], fa[2*q+1], ha[q], la[q]);
            split2(fb[2*q], fb[2*q+1], hb[q], lb[q]);
        }
        *(uint4*)&Ah[kc0    ][r][0] = make_uint4(ha[0], ha[1], ha[2], ha[3]);
        *(uint4*)&Ah[kc0 + 1][r][0] = make_uint4(ha[4], ha[5], ha[6], ha[7]);
        *(uint4*)&Al[kc0    ][r][0] = make_uint4(la[0], la[1], la[2], la[3]);
        *(uint4*)&Al[kc0 + 1][r][0] = make_uint4(la[4], la[5], la[6], la[7]);
        *(uint4*)&Bh[kc0    ][r][0] = make_uint4(hb[0], hb[1], hb[2], hb[3]);
        *(uint4*)&Bh[kc0 + 1][r][0] = make_uint4(hb[4], hb[5], hb[6], hb[7]);
        *(uint4*)&Bl[kc0    ][r][0] = make_uint4(lb[0], lb[1], lb[2], lb[3]);
        *(uint4*)&Bl[kc0 + 1][r][0] = make_uint4(lb[4], lb[5], lb[6], lb[7]);

        __syncthreads();   // tiles staged

        short8v a_h[4], a_l[4], b_h[4], b_l[4];
        #pragma unroll
        for (int i = 0; i < 4; i++) {
            a_h[i] = *(const short8v*)&Ah[kg][wr * 64 + i * 16 + fr][0];
            a_l[i] = *(const short8v*)&Al[kg][wr * 64 + i * 16 + fr][0];
            b_h[i] = *(const short8v*)&Bh[kg][wc * 64 + i * 16 + fr][0];
            b_l[i] = *(const short8v*)&Bl[kg][wc * 64 + i * 16 + fr][0];
        }
        #pragma unroll
        for (int i = 0; i < 4; i++)
            #pragma unroll
            for (int j = 0; j < 4; j++) {
                acc[i][j] = __builtin_amdgcn_mfma_f32_16x16x32_bf16(
                                a_h[i], b_h[j], acc[i][j], 0, 0, 0);
                acc[i][j] = __builtin_amdgcn_mfma_f32_16x16x32_bf16(
                                a_h[i], b_l[j], acc[i][j], 0, 0, 0);
                acc[i][j] = __builtin_amdgcn_mfma_f32_16x16x32_bf16(
                                a_l[i], b_h[j], acc[i][j], 0, 0, 0);
            }
    }

    const int rg = (lane >> 4) * 4;
    #pragma unroll
    for (int i = 0; i < 4; i++) {
        const size_t row0 = (size_t)(bm + wr * 64 + i * 16 + rg);
        #pragma unroll
        for (int j = 0; j < 4; j++) {
            const int col = bn + wc * 64 + j * 16 + fr;
            const float bb = bias[col];
            float* o = out + row0 * 1024 + col;
            o[0]        = acc[i][j][0] + bb;
            o[1024]     = acc[i][j][1] + bb;
            o[2048]     = acc[i][j][2] + bb;
            o[3072]     = acc[i][j][3] + bb;
        }
    }
}

// ---------------------------------------------------------------------------
// Forward FFT core, radix-2 DIF on split padded re/im arrays.
// natural-order input -> bit-reversed-order output. 512 threads, N=1024.
// ---------------------------------------------------------------------------
__device__ __forceinline__ void fft_fwd_core(float* re, float* im,
                                             const float2* twid)
{
    const int tid = threadIdx.x;
    for (int s = 10; s >= 1; s--) {
        __syncthreads();
        const int half = 1 << (s - 1);
        const int j    = tid & (half - 1);
        const int base = ((tid >> (s - 1)) << s) + j;
        const int i0 = lpad(base), i1 = lpad(base + half);
        float ax = re[i0], ay = im[i0];
        float bx = re[i1], by = im[i1];
        float2 w = twid[j << (10 - s)];
        float dx = ax - bx, dy = ay - by;
        re[i0] = ax + bx;  im[i0] = ay + by;
        re[i1] = dx * w.x - dy * w.y;
        im[i1] = dx * w.y + dy * w.x;
    }
    __syncthreads();
}

// ---------------------------------------------------------------------------
// FFT of k-linear rows -> store Kf into kvp.
// ---------------------------------------------------------------------------
__global__ __launch_bounds__(512) void fftK_kernel(const float* __restrict__ lin0,
                                                   float2* __restrict__ kvp)
{
    __shared__ float bre[1056], bim[1056];
    __shared__ float2 twid[512];
    const int tid = threadIdx.x;
    const size_t row = blockIdx.x;

    float ang = -6.283185307179586f * (float)tid * (1.0f / 1024.0f);
    float sv, cv;
    sincosf(ang, &sv, &cv);
    twid[tid] = make_float2(cv, sv);

    const float* src = lin0 + row * ND;
    bre[lpad(tid)]       = src[tid];       bim[lpad(tid)]       = 0.0f;
    bre[lpad(tid + 512)] = src[tid + 512]; bim[lpad(tid + 512)] = 0.0f;
    // first __syncthreads inside fft_fwd_core covers twid + loads

    fft_fwd_core(bre, bim, twid);
    kvp[row * ND + tid]       = make_float2(bre[lpad(tid)],       bim[lpad(tid)]);
    kvp[row * ND + tid + 512] = make_float2(bre[lpad(tid + 512)], bim[lpad(tid + 512)]);
}

// ---------------------------------------------------------------------------
// FFT of v-linear rows; kvp := kvp * Vf  (in place).
// ---------------------------------------------------------------------------
__global__ __launch_bounds__(512) void fftV_kernel(const float* __restrict__ lin0,
                                                   float2* __restrict__ kvp)
{
    __shared__ float bre[1056], bim[1056];
    __shared__ float2 twid[512];
    const int tid = threadIdx.x;
    const size_t row = blockIdx.x;

    float ang = -6.283185307179586f * (float)tid * (1.0f / 1024.0f);
    float sv, cv;
    sincosf(ang, &sv, &cv);
    twid[tid] = make_float2(cv, sv);

    const float* src = lin0 + row * ND;
    bre[lpad(tid)]       = src[tid];       bim[lpad(tid)]       = 0.0f;
    bre[lpad(tid + 512)] = src[tid + 512]; bim[lpad(tid + 512)] = 0.0f;

    fft_fwd_core(bre, bim, twid);
    float2 v0 = make_float2(bre[lpad(tid)],       bim[lpad(tid)]);
    float2 v1 = make_float2(bre[lpad(tid + 512)], bim[lpad(tid + 512)]);
    float2 k0 = kvp[row * ND + tid];
    float2 k1 = kvp[row * ND + tid + 512];
    kvp[row * ND + tid]       = c_mul(k0, v0);
    kvp[row * ND + tid + 512] = c_mul(k1, v1);
}

// ---------------------------------------------------------------------------
// Kernels 3a/3b/3c: chunked inclusive scan of kvp along S (per b, per d).
// ---------------------------------------------------------------------------
__global__ __launch_bounds__(256) void scan_chunk_kernel(const float2* __restrict__ kvp,
                                                         float2* __restrict__ cs)
{
    const int d = blockIdx.x * 256 + threadIdx.x;
    const int c = blockIdx.y;
    const int b = blockIdx.z;
    float2 acc = make_float2(0.f, 0.f);
    size_t base = ((size_t)b * SLEN + (size_t)c * CHLEN) * ND + d;
    for (int i = 0; i < CHLEN; i++) {
        acc = c_add(acc, kvp[base + (size_t)i * ND]);
    }
    cs[((size_t)b * CHUNKS + c) * ND + d] = acc;
}

__global__ __launch_bounds__(256) void scan_prefix_kernel(float2* __restrict__ cs)
{
    const int d = blockIdx.x * 256 + threadIdx.x;
    const int b = blockIdx.y;
    float2 run = make_float2(0.f, 0.f);
    for (int c = 0; c < CHUNKS; c++) {
        size_t idx = ((size_t)b * CHUNKS + c) * ND + d;
        float2 t = cs[idx];
        cs[idx] = run;          // exclusive prefix
        run = c_add(run, t);
    }
}

__global__ __launch_bounds__(256) void scan_apply_kernel(float2* __restrict__ kvp,
                                                         const float2* __restrict__ cs)
{
    const int d = blockIdx.x * 256 + threadIdx.x;
    const int c = blockIdx.y;
    const int b = blockIdx.z;
    float2 run = cs[((size_t)b * CHUNKS + c) * ND + d];
    size_t base = ((size_t)b * SLEN + (size_t)c * CHLEN) * ND + d;
    for (int i = 0; i < CHLEN; i++) {
        size_t idx = base + (size_t)i * ND;
        run = c_add(run, kvp[idx]);
        kvp[idx] = run;         // in-place -> inclusive cumsum
    }
}

// ---------------------------------------------------------------------------
// Final: q-linear row lives in `out`; FFT it (DIF), u = kvcum*conj(Qf),
// L2-normalize over D, inverse FFT (DIT, bit-reversed -> natural),
// out = real * (1/1024) * (1/32).
// ---------------------------------------------------------------------------
__global__ __launch_bounds__(512) void final_kernel(const float2* __restrict__ kvc,
                                                    float* __restrict__ out)
{
    __shared__ float bre[1056], bim[1056];
    __shared__ float2 twid[512];
    __shared__ float red[8];
    const int tid = threadIdx.x;
    const size_t row = blockIdx.x;

    float ang = -6.283185307179586f * (float)tid * (1.0f / 1024.0f);
    float sv, cv;
    sincosf(ang, &sv, &cv);
    twid[tid] = make_float2(cv, sv);

    // forward FFT of the q-linear row (stored in out)
    const float* src = out + row * ND;
    bre[lpad(tid)]       = src[tid];       bim[lpad(tid)]       = 0.0f;
    bre[lpad(tid + 512)] = src[tid + 512]; bim[lpad(tid + 512)] = 0.0f;
    fft_fwd_core(bre, bim, twid);
    float2 q0 = make_float2(bre[lpad(tid)],       bim[lpad(tid)]);
    float2 q1 = make_float2(bre[lpad(tid + 512)], bim[lpad(tid + 512)]);

    float2 kv0 = kvc[row * ND + tid];
    float2 kv1 = kvc[row * ND + tid + 512];
    float2 u0 = c_mul(kv0, make_float2(q0.x, -q0.y));
    float2 u1 = c_mul(kv1, make_float2(q1.x, -q1.y));

    float p = u0.x * u0.x + u0.y * u0.y + u1.x * u1.x + u1.y * u1.y;
    #pragma unroll
    for (int off = 32; off >= 1; off >>= 1) p += __shfl_xor(p, off, 64);
    __syncthreads();               // q reads done before overwrite
    if ((tid & 63) == 0) red[tid >> 6] = p;
    bre[lpad(tid)]       = u0.x;  bim[lpad(tid)]       = u0.y;
    bre[lpad(tid + 512)] = u1.x;  bim[lpad(tid + 512)] = u1.y;
    __syncthreads();
    float ssum = 0.0f;
    #pragma unroll
    for (int i = 0; i < 8; i++) ssum += red[i];
    // scale = 1/(1e-9+nrm) * (1/N for ifft) * (1/sqrt(D))
    const float scale = 1.0f / (1e-9f + sqrtf(ssum)) * (1.0f / 32768.0f);

    // inverse DIT, bit-reversed input, twiddles conj(twid)
    for (int s = 1; s <= 10; s++) {
        __syncthreads();
        const int half = 1 << (s - 1);
        const int j    = tid & (half - 1);
        const int base = ((tid >> (s - 1)) << s) + j;
        const int i0 = lpad(base), i1 = lpad(base + half);
        float ax = bre[i0], ay = bim[i0];
        float bx = bre[i1], by = bim[i1];
        float2 w = twid[j << (10 - s)];
        // t = b * conj(w)
        float tx = bx * w.x + by * w.y;
        float ty = by * w.x - bx * w.y;
        bre[i0] = ax + tx;  bim[i0] = ay + ty;
        bre[i1] = ax - tx;  bim[i1] = ay - ty;
    }
    __syncthreads();
    out[row * ND + tid]       = bre[lpad(tid)]       * scale;
    out[row * ND + tid + 512] = bre[lpad(tid + 512)] * scale;
}

// ---------------------------------------------------------------------------
// Diagnostic: workspace too small -> make absmax show ws_size (no crash).
// ---------------------------------------------------------------------------
__global__ void ws_diag_kernel(float* __restrict__ out, float wsz)
{
    if (threadIdx.x == 0 && blockIdx.x == 0) out[0] = wsz;
}

// ---------------------------------------------------------------------------
extern "C" void kernel_launch(void* const* d_in, const int* in_sizes, int n_in,
                              void* d_out, int out_size, void* d_ws, size_t ws_size,
                              hipStream_t stream)
{
    const float* x  = (const float*)d_in[0];
    const float* Wk = (const float*)d_in[1];
    const float* bk = (const float*)d_in[2];
    const float* Wv = (const float*)d_in[3];
    const float* bv = (const float*)d_in[4];
    const float* Wq = (const float*)d_in[5];
    const float* bq = (const float*)d_in[6];
    float* out = (float*)d_out;

    if (ws_size < WS_NEEDED) {
        ws_diag_kernel<<<1, 64, 0, stream>>>(out, (float)ws_size);
        return;
    }

    char* ws = (char*)d_ws;
    float2* kvp  = (float2*)ws;                                  // 134217728 B
    float*  lin0 = (float*)(ws + WS_KVP_BYTES);                  //  67108864 B
    float2* cs   = (float2*)(ws + WS_KVP_BYTES + WS_LIN_BYTES);  //    524288 B

    // q projection -> d_out (used as scratch; final kernel re-reads it)
    gemm_kernel<<<dim3(8, 128), 256, 0, stream>>>(x, Wq, bq, out);
    // k projection -> lin0; FFT -> kvp
    gemm_kernel<<<dim3(8, 128), 256, 0, stream>>>(x, Wk, bk, lin0);
    fftK_kernel<<<dim3(MROWS), 512, 0, stream>>>(lin0, kvp);
    // v projection -> lin0 (reused); FFT and multiply in place
    gemm_kernel<<<dim3(8, 128), 256, 0, stream>>>(x, Wv, bv, lin0);
    fftV_kernel<<<dim3(MROWS), 512, 0, stream>>>(lin0, kvp);
    // causal cumsum along S
    scan_chunk_kernel<<<dim3(4, CHUNKS, NB), 256, 0, stream>>>(kvp, cs);
    scan_prefix_kernel<<<dim3(4, NB), 256, 0, stream>>>(cs);
    scan_apply_kernel<<<dim3(4, CHUNKS, NB), 256, 0, stream>>>(kvp, cs);
    // unbind + normalize + ifft
    final_kernel<<<dim3(MROWS), 512, 0, stream>>>(kvp, out);
}